// Round 1
// baseline (470.724 us; speedup 1.0000x reference)
//
#include <hip/hip_runtime.h>

#define NPTS 4096
#define DIM  256
#define CAND_MAX 256

typedef _Float16 f16;
typedef __attribute__((ext_vector_type(4))) _Float16 f16x4;
typedef __attribute__((ext_vector_type(8))) _Float16 f16x8;
typedef __attribute__((ext_vector_type(4))) float f32x4;

// ---------- block-wide reductions (256 threads = 4 waves) ----------
__device__ __forceinline__ float blk_max(float v, float* sh) {
  #pragma unroll
  for (int off = 32; off; off >>= 1) v = fmaxf(v, __shfl_down(v, off));
  int lane = threadIdx.x & 63, w = threadIdx.x >> 6;
  __syncthreads();
  if (lane == 0) sh[w] = v;
  __syncthreads();
  return fmaxf(fmaxf(sh[0], sh[1]), fmaxf(sh[2], sh[3]));
}

__device__ __forceinline__ float blk_sum(float v, float* sh) {
  #pragma unroll
  for (int off = 32; off; off >>= 1) v += __shfl_down(v, off);
  int lane = threadIdx.x & 63, w = threadIdx.x >> 6;
  __syncthreads();
  if (lane == 0) sh[w] = v;
  __syncthreads();
  return sh[0] + sh[1] + sh[2] + sh[3];
}

// ---------- K1: fp16 hi/lo split + row sumsq (bb) + global sumsq ----------
__global__ __launch_bounds__(256) void split_kernel(
    const float* __restrict__ src, f16* __restrict__ hi, f16* __restrict__ lo,
    float* __restrict__ bb, float* __restrict__ sumsq)
{
  int lane = threadIdx.x & 63;
  int wave = threadIdx.x >> 6;
  int row  = blockIdx.x * 4 + wave;
  const float4 v = *reinterpret_cast<const float4*>(src + (size_t)row * DIM + lane * 4);
  float xs[4] = {v.x, v.y, v.z, v.w};
  f16x4 h, l;
  float ss = 0.f;
  #pragma unroll
  for (int e = 0; e < 4; ++e) {
    f16 he = (f16)xs[e];
    h[e] = he;
    l[e] = (f16)(xs[e] - (float)he);
    ss += xs[e] * xs[e];
  }
  *reinterpret_cast<f16x4*>(hi + (size_t)row * DIM + lane * 4) = h;
  *reinterpret_cast<f16x4*>(lo + (size_t)row * DIM + lane * 4) = l;
  if (bb) {
    #pragma unroll
    for (int off = 32; off; off >>= 1) ss += __shfl_down(ss, off);
    if (lane == 0) { bb[row] = ss; atomicAdd(sumsq, ss); }
  }
}

// ---------- K2: S = x @ y^T via fp16 split (hh + hl + lh), fp32 out ----------
// block = 256 thr = 4 waves (2x2), tile 128x128, K = 256 (8 steps of 32)
__global__ __launch_bounds__(256) void gemm_kernel(
    const f16* __restrict__ Xh, const f16* __restrict__ Xl,
    const f16* __restrict__ Yph, const f16* __restrict__ Ypl,
    const f16* __restrict__ Ynh, const f16* __restrict__ Ynl,
    float* __restrict__ Sp, float* __restrict__ Sn, int rowBase)
{
  const f16* Bh; const f16* Bl; float* S;
  if (blockIdx.z == 0) { Bh = Yph; Bl = Ypl; S = Sp; }
  else                 { Bh = Ynh; Bl = Ynl; S = Sn; }

  const int lane = threadIdx.x & 63;
  const int wave = threadIdx.x >> 6;
  const int wm = wave >> 1, wn = wave & 1;
  const int l15 = lane & 15, lhi = lane >> 4;

  const int rfLocal = blockIdx.x * 128 + wm * 64;   // row within chunk
  const int rfGlob  = rowBase + rfLocal;            // row in x
  const int cf      = blockIdx.y * 128 + wn * 64;   // col = y row index

  f32x4 acc[4][4] = {};

  #pragma unroll 2
  for (int ks = 0; ks < 8; ++ks) {
    const int kk = ks * 32 + lhi * 8;
    f16x8 ah[4], al[4], bh[4], bl[4];
    #pragma unroll
    for (int mi = 0; mi < 4; ++mi) {
      size_t o = (size_t)(rfGlob + mi * 16 + l15) * DIM + kk;
      ah[mi] = *reinterpret_cast<const f16x8*>(Xh + o);
      al[mi] = *reinterpret_cast<const f16x8*>(Xl + o);
    }
    #pragma unroll
    for (int ni = 0; ni < 4; ++ni) {
      size_t o = (size_t)(cf + ni * 16 + l15) * DIM + kk;
      bh[ni] = *reinterpret_cast<const f16x8*>(Bh + o);
      bl[ni] = *reinterpret_cast<const f16x8*>(Bl + o);
    }
    #pragma unroll
    for (int mi = 0; mi < 4; ++mi)
      #pragma unroll
      for (int ni = 0; ni < 4; ++ni) {
        acc[mi][ni] = __builtin_amdgcn_mfma_f32_16x16x32_f16(ah[mi], bh[ni], acc[mi][ni], 0, 0, 0);
        acc[mi][ni] = __builtin_amdgcn_mfma_f32_16x16x32_f16(ah[mi], bl[ni], acc[mi][ni], 0, 0, 0);
        acc[mi][ni] = __builtin_amdgcn_mfma_f32_16x16x32_f16(al[mi], bh[ni], acc[mi][ni], 0, 0, 0);
      }
  }

  // C/D layout: col = lane&15, row = (lane>>4)*4 + r   [m89-verified]
  #pragma unroll
  for (int mi = 0; mi < 4; ++mi)
    #pragma unroll
    for (int ni = 0; ni < 4; ++ni) {
      int col = cf + ni * 16 + l15;
      #pragma unroll
      for (int r = 0; r < 4; ++r) {
        int rw = rfLocal + mi * 16 + lhi * 4 + r;
        S[(size_t)rw * NPTS + col] = acc[mi][ni][r];
      }
    }
}

// ---------- K3: per-row softmax stats + sparse candidate gather ----------
// one block (256 thr) per x-row; thread t owns output dim t.
__global__ __launch_bounds__(256) void row_kernel(
    const float* __restrict__ Sp, const float* __restrict__ Sn,
    const float* __restrict__ bbp, const float* __restrict__ bbn,
    const float* __restrict__ ypos, const float* __restrict__ yneg,
    float* __restrict__ accums, float* __restrict__ Vout, int rowBase)
{
  __shared__ float u[NPTS];
  __shared__ int  list[CAND_MAX];
  __shared__ int  cnt;
  __shared__ float red[4];

  const int tid = threadIdx.x;
  const int local = blockIdx.x;
  const int row = rowBase + local;

  // scale^2 = mean(ref^2) + EPS  (logits are divided by scale^2 * tau)
  const float scalesq = accums[0] * (1.0f / (2.0f * NPTS * DIM)) + 1e-8f;
  const float c0 = 1.0f / (scalesq * 0.02f);
  const float c1 = 1.0f / (scalesq * 0.05f);
  const float c2 = 1.0f / (scalesq * 0.2f);
  const float thr = 30.0f * scalesq * 0.2f;  // keep if (m-u) < thr; e^-30 dropped

  float V0 = 0.f, V1 = 0.f, V2 = 0.f;

  for (int side = 0; side < 2; ++side) {
    const float* S  = side ? Sn : Sp;
    const float* bb = side ? bbn : bbp;
    const float* y  = side ? yneg : ypos;
    const float sgn = side ? -1.f : 1.f;

    float uv[16];
    float mx = -3.0e38f;
    #pragma unroll
    for (int e = 0; e < 16; ++e) {
      int j = e * 256 + tid;
      float s = S[(size_t)local * NPTS + j];
      float t = 2.0f * s - bb[j];
      uv[e] = t;
      u[j] = t;
      mx = fmaxf(mx, t);
    }
    float m = blk_max(mx, red);

    float p0 = 0.f, p1 = 0.f, p2 = 0.f;
    #pragma unroll
    for (int e = 0; e < 16; ++e) {
      float du = uv[e] - m;
      p0 += expf(du * c0);
      p1 += expf(du * c1);
      p2 += expf(du * c2);
    }
    float il0 = 1.0f / blk_sum(p0, red);
    float il1 = 1.0f / blk_sum(p1, red);
    float il2 = 1.0f / blk_sum(p2, red);

    if (tid == 0) cnt = 0;
    __syncthreads();
    #pragma unroll
    for (int e = 0; e < 16; ++e) {
      if (uv[e] > m - thr) {
        int idx = atomicAdd(&cnt, 1);
        if (idx < CAND_MAX) list[idx] = e * 256 + tid;
      }
    }
    __syncthreads();
    int nc = min(cnt, CAND_MAX);
    for (int ci = 0; ci < nc; ++ci) {
      int j = list[ci];
      float du = u[j] - m;
      float yv = y[(size_t)j * DIM + tid];
      V0 += sgn * expf(du * c0) * il0 * yv;
      V1 += sgn * expf(du * c1) * il1 * yv;
      V2 += sgn * expf(du * c2) * il2 * yv;
    }
    __syncthreads();  // before next side overwrites u[]
  }

  float vr = (V0 + V1 + V2) * (1.0f / 3.0f);
  Vout[(size_t)row * DIM + tid] = vr;

  float s0 = blk_sum(V0 * V0, red);
  float s1 = blk_sum(V1 * V1, red);
  float s2 = blk_sum(V2 * V2, red);
  float sr = blk_sum(vr * vr, red);
  if (tid == 0) {
    atomicAdd(accums + 1, sr);
    atomicAdd(accums + 2, s0);
    atomicAdd(accums + 3, s1);
    atomicAdd(accums + 4, s2);
  }
}

// ---------- K4: finalize scalars + scale V by 1/lambda ----------
__global__ __launch_bounds__(256) void final_kernel(
    const float* __restrict__ accums, float* __restrict__ out)
{
  float raw  = accums[1] * (1.0f / NPTS);
  float lam2 = raw * (1.0f / DIM) + 1e-8f;
  float lam  = sqrtf(lam2);
  float inv  = 1.0f / lam;
  size_t idx = (size_t)blockIdx.x * 256 + threadIdx.x;
  out[7 + idx] *= inv;
  if (blockIdx.x == 0 && threadIdx.x == 0) {
    float drift = raw / lam2;
    out[0] = drift * (1.0f / DIM);     // loss = mean(V^2) = drift_norm / D
    out[1] = drift;                    // drift_norm
    out[2] = raw;                      // raw_drift_norm
    out[3] = lam;                      // lambda_V
    out[4] = accums[2] * (1.0f / NPTS);
    out[5] = accums[3] * (1.0f / NPTS);
    out[6] = accums[4] * (1.0f / NPTS);
  }
}

extern "C" void kernel_launch(void* const* d_in, const int* in_sizes, int n_in,
                              void* d_out, int out_size, void* d_ws, size_t ws_size,
                              hipStream_t stream)
{
  (void)in_sizes; (void)n_in; (void)out_size;
  const float* x    = (const float*)d_in[0];
  const float* ypos = (const float*)d_in[1];
  const float* yneg = (const float*)d_in[2];
  float* out = (float*)d_out;
  char* ws = (char*)d_ws;

  // ws layout: [accums 8f | bbp 16KB | bbn 16KB | 6 fp16 splits 12MB | S chunks]
  float* accums = (float*)ws;
  float* bbp = (float*)(ws + 256);
  float* bbn = (float*)(ws + 256 + 4 * NPTS);
  const size_t NM = (size_t)NPTS * DIM;
  f16* xh  = (f16*)(ws + 33024);
  f16* xl  = xh + NM;
  f16* yph = xh + 2 * NM;
  f16* ypl = xh + 3 * NM;
  f16* ynh = xh + 4 * NM;
  f16* ynl = xh + 5 * NM;
  float* Sbase = (float*)(ws + 33024 + 6 * NM * sizeof(f16));
  size_t fixedBytes = 33024 + 6 * NM * sizeof(f16);
  size_t avail = ws_size > fixedBytes ? ws_size - fixedBytes : 0;

  int R = 128;                                   // chunk of x rows materialized
  if      (avail >= 2ull * 4096 * NPTS * 4) R = 4096;
  else if (avail >= 2ull * 2048 * NPTS * 4) R = 2048;
  else if (avail >= 2ull * 1024 * NPTS * 4) R = 1024;
  else if (avail >= 2ull * 512  * NPTS * 4) R = 512;
  else if (avail >= 2ull * 256  * NPTS * 4) R = 256;
  float* Sp = Sbase;
  float* Sn = Sbase + (size_t)R * NPTS;

  hipMemsetAsync(accums, 0, 32, stream);
  split_kernel<<<NPTS / 4, 256, 0, stream>>>(x,    xh,  xl,  nullptr, nullptr);
  split_kernel<<<NPTS / 4, 256, 0, stream>>>(ypos, yph, ypl, bbp, accums);
  split_kernel<<<NPTS / 4, 256, 0, stream>>>(yneg, ynh, ynl, bbn, accums);

  for (int base = 0; base < NPTS; base += R) {
    dim3 g(R / 128, NPTS / 128, 2);
    gemm_kernel<<<g, 256, 0, stream>>>(xh, xl, yph, ypl, ynh, ynl, Sp, Sn, base);
    row_kernel<<<R, 256, 0, stream>>>(Sp, Sn, bbp, bbn, ypos, yneg, accums, out + 7, base);
  }
  final_kernel<<<NPTS, 256, 0, stream>>>(accums, out);
}

// Round 2
// 469.190 us; speedup vs baseline: 1.0033x; 1.0033x over previous
//
#include <hip/hip_runtime.h>

#define NPTS 4096
#define DIM  256
#define CAND_MAX 256

typedef _Float16 f16;
typedef __attribute__((ext_vector_type(4))) _Float16 f16x4;
typedef __attribute__((ext_vector_type(8))) _Float16 f16x8;
typedef __attribute__((ext_vector_type(4))) float f32x4;

__device__ __forceinline__ float exp2fast(float x) {
  float r;
  asm("v_exp_f32 %0, %1" : "=v"(r) : "v"(x));
  return r;
}

// ---------- block-wide reductions (256 threads = 4 waves) ----------
__device__ __forceinline__ float blk_max(float v, float* sh) {
  #pragma unroll
  for (int off = 32; off; off >>= 1) v = fmaxf(v, __shfl_down(v, off));
  int lane = threadIdx.x & 63, w = threadIdx.x >> 6;
  __syncthreads();
  if (lane == 0) sh[w] = v;
  __syncthreads();
  return fmaxf(fmaxf(sh[0], sh[1]), fmaxf(sh[2], sh[3]));
}

__device__ __forceinline__ float blk_sum(float v, float* sh) {
  #pragma unroll
  for (int off = 32; off; off >>= 1) v += __shfl_down(v, off);
  int lane = threadIdx.x & 63, w = threadIdx.x >> 6;
  __syncthreads();
  if (lane == 0) sh[w] = v;
  __syncthreads();
  return sh[0] + sh[1] + sh[2] + sh[3];
}

// ---------- K1: fp16 hi/lo split + row sumsq (bb) + global sumsq ----------
__global__ __launch_bounds__(256) void split_kernel(
    const float* __restrict__ src, f16* __restrict__ hi, f16* __restrict__ lo,
    float* __restrict__ bb, float* __restrict__ sumsq)
{
  int lane = threadIdx.x & 63;
  int wave = threadIdx.x >> 6;
  int row  = blockIdx.x * 4 + wave;
  const float4 v = *reinterpret_cast<const float4*>(src + (size_t)row * DIM + lane * 4);
  float xs[4] = {v.x, v.y, v.z, v.w};
  f16x4 h, l;
  float ss = 0.f;
  #pragma unroll
  for (int e = 0; e < 4; ++e) {
    f16 he = (f16)xs[e];
    h[e] = he;
    l[e] = (f16)(xs[e] - (float)he);
    ss += xs[e] * xs[e];
  }
  *reinterpret_cast<f16x4*>(hi + (size_t)row * DIM + lane * 4) = h;
  *reinterpret_cast<f16x4*>(lo + (size_t)row * DIM + lane * 4) = l;
  if (bb) {
    #pragma unroll
    for (int off = 32; off; off >>= 1) ss += __shfl_down(ss, off);
    if (lane == 0) { bb[row] = ss; atomicAdd(sumsq, ss); }
  }
}

// ---------- K2: S = x @ y^T via fp16 split (hh + hl + lh), fp32 out ----------
__global__ __launch_bounds__(256) void gemm_kernel(
    const f16* __restrict__ Xh, const f16* __restrict__ Xl,
    const f16* __restrict__ Yph, const f16* __restrict__ Ypl,
    const f16* __restrict__ Ynh, const f16* __restrict__ Ynl,
    float* __restrict__ Sp, float* __restrict__ Sn, int rowBase)
{
  const f16* Bh; const f16* Bl; float* S;
  if (blockIdx.z == 0) { Bh = Yph; Bl = Ypl; S = Sp; }
  else                 { Bh = Ynh; Bl = Ynl; S = Sn; }

  const int lane = threadIdx.x & 63;
  const int wave = threadIdx.x >> 6;
  const int wm = wave >> 1, wn = wave & 1;
  const int l15 = lane & 15, lhi = lane >> 4;

  const int rfLocal = blockIdx.x * 128 + wm * 64;
  const int rfGlob  = rowBase + rfLocal;
  const int cf      = blockIdx.y * 128 + wn * 64;

  f32x4 acc[4][4] = {};

  #pragma unroll 2
  for (int ks = 0; ks < 8; ++ks) {
    const int kk = ks * 32 + lhi * 8;
    f16x8 ah[4], al[4], bh[4], bl[4];
    #pragma unroll
    for (int mi = 0; mi < 4; ++mi) {
      size_t o = (size_t)(rfGlob + mi * 16 + l15) * DIM + kk;
      ah[mi] = *reinterpret_cast<const f16x8*>(Xh + o);
      al[mi] = *reinterpret_cast<const f16x8*>(Xl + o);
    }
    #pragma unroll
    for (int ni = 0; ni < 4; ++ni) {
      size_t o = (size_t)(cf + ni * 16 + l15) * DIM + kk;
      bh[ni] = *reinterpret_cast<const f16x8*>(Bh + o);
      bl[ni] = *reinterpret_cast<const f16x8*>(Bl + o);
    }
    #pragma unroll
    for (int mi = 0; mi < 4; ++mi)
      #pragma unroll
      for (int ni = 0; ni < 4; ++ni) {
        acc[mi][ni] = __builtin_amdgcn_mfma_f32_16x16x32_f16(ah[mi], bh[ni], acc[mi][ni], 0, 0, 0);
        acc[mi][ni] = __builtin_amdgcn_mfma_f32_16x16x32_f16(ah[mi], bl[ni], acc[mi][ni], 0, 0, 0);
        acc[mi][ni] = __builtin_amdgcn_mfma_f32_16x16x32_f16(al[mi], bh[ni], acc[mi][ni], 0, 0, 0);
      }
  }

  // C/D layout: col = lane&15, row = (lane>>4)*4 + r   [m89-verified]
  #pragma unroll
  for (int mi = 0; mi < 4; ++mi)
    #pragma unroll
    for (int ni = 0; ni < 4; ++ni) {
      int col = cf + ni * 16 + l15;
      #pragma unroll
      for (int r = 0; r < 4; ++r) {
        int rw = rfLocal + mi * 16 + lhi * 4 + r;
        S[(size_t)rw * NPTS + col] = acc[mi][ni][r];
      }
    }
}

// ---------- K3: per-row max + sparse candidate softmax/gather ----------
// one block (256 thr) per x-row; thread t owns j in [16t,16t+16) for the scan
// and output dim t for the V accumulation.
__global__ __launch_bounds__(256) void row_kernel(
    const float* __restrict__ Sp, const float* __restrict__ Sn,
    const float* __restrict__ bbp, const float* __restrict__ bbn,
    const float* __restrict__ ypos, const float* __restrict__ yneg,
    float* __restrict__ accums, float* __restrict__ Vout, int rowBase)
{
  __shared__ int   jlist[CAND_MAX];
  __shared__ float dulist[CAND_MAX];
  __shared__ float we0[CAND_MAX];
  __shared__ float we1[CAND_MAX];
  __shared__ float we2[CAND_MAX];
  __shared__ int   cnt;
  __shared__ float red[4];

  const int tid = threadIdx.x;
  const int local = blockIdx.x;
  const int row = rowBase + local;

  // scale^2 = mean(ref^2) + EPS; logits u/(scale^2 * tau), exp via 2^x
  const float scalesq = accums[0] * (1.0f / (2.0f * NPTS * DIM)) + 1e-8f;
  const float L2E = 1.4426950408889634f;
  const float c0 = L2E / (scalesq * 0.02f);
  const float c1 = L2E / (scalesq * 0.05f);
  const float c2 = L2E / (scalesq * 0.2f);
  const float thr = 30.0f * scalesq * 0.2f;  // dropped terms < e^-30

  float V0 = 0.f, V1 = 0.f, V2 = 0.f;

  for (int side = 0; side < 2; ++side) {
    const float* S  = side ? Sn : Sp;
    const float* bb = side ? bbn : bbp;
    const float* y  = side ? yneg : ypos;
    const float sgn = side ? -1.f : 1.f;

    // ---- max pass: thread t owns 16 contiguous j, float4 loads ----
    float uv[16];
    float mx = -3.0e38f;
    const float* Srow = S + (size_t)local * NPTS + tid * 16;
    const float* bbt  = bb + tid * 16;
    #pragma unroll
    for (int q = 0; q < 4; ++q) {
      float4 s4 = *reinterpret_cast<const float4*>(Srow + q * 4);
      float4 b4 = *reinterpret_cast<const float4*>(bbt + q * 4);
      uv[q * 4 + 0] = 2.0f * s4.x - b4.x;
      uv[q * 4 + 1] = 2.0f * s4.y - b4.y;
      uv[q * 4 + 2] = 2.0f * s4.z - b4.z;
      uv[q * 4 + 3] = 2.0f * s4.w - b4.w;
      mx = fmaxf(mx, fmaxf(fmaxf(uv[q*4], uv[q*4+1]), fmaxf(uv[q*4+2], uv[q*4+3])));
    }
    float m = blk_max(mx, red);

    // ---- candidate detection ----
    if (tid == 0) cnt = 0;
    __syncthreads();
    #pragma unroll
    for (int e = 0; e < 16; ++e) {
      float du = uv[e] - m;
      if (du > -thr) {
        int idx = atomicAdd(&cnt, 1);
        if (idx < CAND_MAX) { jlist[idx] = tid * 16 + e; dulist[idx] = du; }
      }
    }
    __syncthreads();
    int nc = min(cnt, CAND_MAX);

    // ---- candidate exps (thread-strided) ----
    for (int ci = tid; ci < nc; ci += 256) {
      float du = dulist[ci];
      we0[ci] = exp2fast(du * c0);
      we1[ci] = exp2fast(du * c1);
      we2[ci] = exp2fast(du * c2);
    }
    __syncthreads();

    // ---- p sums (LDS broadcast, redundant per thread; nc is small) ----
    float p0 = 0.f, p1 = 0.f, p2 = 0.f;
    for (int ci = 0; ci < nc; ++ci) { p0 += we0[ci]; p1 += we1[ci]; p2 += we2[ci]; }
    float il0 = sgn / p0, il1 = sgn / p1, il2 = sgn / p2;

    // ---- V gather: unroll 4 for load overlap ----
    int ci = 0;
    for (; ci + 4 <= nc; ci += 4) {
      float yv[4];
      int jj[4];
      #pragma unroll
      for (int q = 0; q < 4; ++q) jj[q] = jlist[ci + q];
      #pragma unroll
      for (int q = 0; q < 4; ++q) yv[q] = y[(size_t)jj[q] * DIM + tid];
      #pragma unroll
      for (int q = 0; q < 4; ++q) {
        V0 += we0[ci + q] * il0 * yv[q];
        V1 += we1[ci + q] * il1 * yv[q];
        V2 += we2[ci + q] * il2 * yv[q];
      }
    }
    for (; ci < nc; ++ci) {
      float yv = y[(size_t)jlist[ci] * DIM + tid];
      V0 += we0[ci] * il0 * yv;
      V1 += we1[ci] * il1 * yv;
      V2 += we2[ci] * il2 * yv;
    }
    __syncthreads();  // before next side reuses shared
  }

  float vr = (V0 + V1 + V2) * (1.0f / 3.0f);
  Vout[(size_t)row * DIM + tid] = vr;

  float s0 = blk_sum(V0 * V0, red);
  float s1 = blk_sum(V1 * V1, red);
  float s2 = blk_sum(V2 * V2, red);
  float sr = blk_sum(vr * vr, red);
  if (tid == 0) {
    atomicAdd(accums + 1, sr);
    atomicAdd(accums + 2, s0);
    atomicAdd(accums + 3, s1);
    atomicAdd(accums + 4, s2);
  }
}

// ---------- K4: finalize scalars + scale V by 1/lambda ----------
__global__ __launch_bounds__(256) void final_kernel(
    const float* __restrict__ accums, float* __restrict__ out)
{
  float raw  = accums[1] * (1.0f / NPTS);
  float lam2 = raw * (1.0f / DIM) + 1e-8f;
  float lam  = sqrtf(lam2);
  float inv  = 1.0f / lam;
  size_t idx = (size_t)blockIdx.x * 256 + threadIdx.x;
  out[7 + idx] *= inv;
  if (blockIdx.x == 0 && threadIdx.x == 0) {
    float drift = raw / lam2;
    out[0] = drift * (1.0f / DIM);     // loss = mean(V^2) = drift_norm / D
    out[1] = drift;                    // drift_norm
    out[2] = raw;                      // raw_drift_norm
    out[3] = lam;                      // lambda_V
    out[4] = accums[2] * (1.0f / NPTS);
    out[5] = accums[3] * (1.0f / NPTS);
    out[6] = accums[4] * (1.0f / NPTS);
  }
}

extern "C" void kernel_launch(void* const* d_in, const int* in_sizes, int n_in,
                              void* d_out, int out_size, void* d_ws, size_t ws_size,
                              hipStream_t stream)
{
  (void)in_sizes; (void)n_in; (void)out_size;
  const float* x    = (const float*)d_in[0];
  const float* ypos = (const float*)d_in[1];
  const float* yneg = (const float*)d_in[2];
  float* out = (float*)d_out;
  char* ws = (char*)d_ws;

  float* accums = (float*)ws;
  float* bbp = (float*)(ws + 256);
  float* bbn = (float*)(ws + 256 + 4 * NPTS);
  const size_t NM = (size_t)NPTS * DIM;
  f16* xh  = (f16*)(ws + 33024);
  f16* xl  = xh + NM;
  f16* yph = xh + 2 * NM;
  f16* ypl = xh + 3 * NM;
  f16* ynh = xh + 4 * NM;
  f16* ynl = xh + 5 * NM;
  float* Sbase = (float*)(ws + 33024 + 6 * NM * sizeof(f16));
  size_t fixedBytes = 33024 + 6 * NM * sizeof(f16);
  size_t avail = ws_size > fixedBytes ? ws_size - fixedBytes : 0;

  int R = 128;
  if      (avail >= 2ull * 4096 * NPTS * 4) R = 4096;
  else if (avail >= 2ull * 2048 * NPTS * 4) R = 2048;
  else if (avail >= 2ull * 1024 * NPTS * 4) R = 1024;
  else if (avail >= 2ull * 512  * NPTS * 4) R = 512;
  else if (avail >= 2ull * 256  * NPTS * 4) R = 256;
  float* Sp = Sbase;
  float* Sn = Sbase + (size_t)R * NPTS;

  hipMemsetAsync(accums, 0, 32, stream);
  split_kernel<<<NPTS / 4, 256, 0, stream>>>(x,    xh,  xl,  nullptr, nullptr);
  split_kernel<<<NPTS / 4, 256, 0, stream>>>(ypos, yph, ypl, bbp, accums);
  split_kernel<<<NPTS / 4, 256, 0, stream>>>(yneg, ynh, ynl, bbn, accums);

  for (int base = 0; base < NPTS; base += R) {
    dim3 g(R / 128, NPTS / 128, 2);
    gemm_kernel<<<g, 256, 0, stream>>>(xh, xl, yph, ypl, ynh, ynl, Sp, Sn, base);
    row_kernel<<<R, 256, 0, stream>>>(Sp, Sn, bbp, bbn, ypos, yneg, accums, out + 7, base);
  }
  final_kernel<<<NPTS, 256, 0, stream>>>(accums, out);
}

// Round 3
// 136.159 us; speedup vs baseline: 3.4572x; 3.4459x over previous
//
#include <hip/hip_runtime.h>

#define NPTS 4096
#define DIM  256
#define CAND_MAX 256

typedef _Float16 f16;
typedef __attribute__((ext_vector_type(4))) _Float16 f16x4;
typedef __attribute__((ext_vector_type(8))) _Float16 f16x8;
typedef __attribute__((ext_vector_type(4))) float f32x4;

__device__ __forceinline__ float exp2fast(float x) {
  float r;
  asm("v_exp_f32 %0, %1" : "=v"(r) : "v"(x));
  return r;
}

__device__ __forceinline__ void gload_lds16(const void* g, void* l) {
  __builtin_amdgcn_global_load_lds((const __attribute__((address_space(1))) void*)g,
                                   (__attribute__((address_space(3))) void*)l, 16, 0, 0);
}

// ---------- block-wide reductions (256 threads = 4 waves) ----------
__device__ __forceinline__ float blk_max(float v, float* sh) {
  #pragma unroll
  for (int off = 32; off; off >>= 1) v = fmaxf(v, __shfl_down(v, off));
  int lane = threadIdx.x & 63, w = threadIdx.x >> 6;
  __syncthreads();
  if (lane == 0) sh[w] = v;
  __syncthreads();
  return fmaxf(fmaxf(sh[0], sh[1]), fmaxf(sh[2], sh[3]));
}

__device__ __forceinline__ float blk_sum(float v, float* sh) {
  #pragma unroll
  for (int off = 32; off; off >>= 1) v += __shfl_down(v, off);
  int lane = threadIdx.x & 63, w = threadIdx.x >> 6;
  __syncthreads();
  if (lane == 0) sh[w] = v;
  __syncthreads();
  return sh[0] + sh[1] + sh[2] + sh[3];
}

// ---------- K1: fp16 hi/lo split + row sumsq (bb); NO global atomics ----------
__global__ __launch_bounds__(256) void split_kernel(
    const float* __restrict__ src, f16* __restrict__ hi, f16* __restrict__ lo,
    float* __restrict__ bb)
{
  int lane = threadIdx.x & 63;
  int wave = threadIdx.x >> 6;
  int row  = blockIdx.x * 4 + wave;
  const float4 v = *reinterpret_cast<const float4*>(src + (size_t)row * DIM + lane * 4);
  float xs[4] = {v.x, v.y, v.z, v.w};
  f16x4 h, l;
  float ss = 0.f;
  #pragma unroll
  for (int e = 0; e < 4; ++e) {
    f16 he = (f16)xs[e];
    h[e] = he;
    l[e] = (f16)(xs[e] - (float)he);
    ss += xs[e] * xs[e];
  }
  *reinterpret_cast<f16x4*>(hi + (size_t)row * DIM + lane * 4) = h;
  *reinterpret_cast<f16x4*>(lo + (size_t)row * DIM + lane * 4) = l;
  if (bb) {
    #pragma unroll
    for (int off = 32; off; off >>= 1) ss += __shfl_down(ss, off);
    if (lane == 0) bb[row] = ss;
  }
}

// ---------- reduce_ss: accums[0] = sum(bbp) + sum(bbn) ----------
__global__ __launch_bounds__(256) void reduce_ss(
    const float* __restrict__ bbp, const float* __restrict__ bbn, float* __restrict__ accums)
{
  __shared__ float red[4];
  int tid = threadIdx.x;
  float s = 0.f;
  for (int k = tid; k < NPTS; k += 256) s += bbp[k] + bbn[k];
  s = blk_sum(s, red);
  if (tid == 0) accums[0] = s;
}

// ---------- K2: S = x @ y^T via fp16 split, m97-style LDS staging ----------
// block 256 = 4 waves (2x2), tile 128x128, BK=32, single-buffered LDS
__global__ __launch_bounds__(256) void gemm_kernel(
    const f16* __restrict__ Xh, const f16* __restrict__ Xl,
    const f16* __restrict__ Yph, const f16* __restrict__ Ypl,
    const f16* __restrict__ Ynh, const f16* __restrict__ Ynl,
    float* __restrict__ Sp, float* __restrict__ Sn, int rowBase)
{
  __shared__ f16 Ah[128 * 32];
  __shared__ f16 Al[128 * 32];
  __shared__ f16 Bh[128 * 32];
  __shared__ f16 Bl[128 * 32];

  const f16* YBh; const f16* YBl; float* S;
  if (blockIdx.z == 0) { YBh = Yph; YBl = Ypl; S = Sp; }
  else                 { YBh = Ynh; YBl = Ynl; S = Sn; }

  const int tid  = threadIdx.x;
  const int lane = tid & 63;
  const int wave = tid >> 6;
  const int wm = wave >> 1, wn = wave & 1;
  const int l15 = lane & 15, lhi = lane >> 4;

  const int rfLocal = blockIdx.x * 128;
  const int rfGlob  = rowBase + rfLocal;
  const int cf      = blockIdx.y * 128;

  // staging coords: thread covers tile row g*64 + (tid>>2), 16B chunk tid&3
  const int srow = tid >> 2;
  const int schk = tid & 3;

  f32x4 acc[4][4] = {};

  #pragma unroll 1
  for (int ks = 0; ks < 8; ++ks) {
    const int kk = ks * 32 + schk * 8;
    #pragma unroll
    for (int g = 0; g < 2; ++g) {
      int r = g * 64 + srow;
      size_t ao = (size_t)(rfGlob + r) * DIM + kk;
      size_t bo = (size_t)(cf     + r) * DIM + kk;
      int ld = r * 32 + schk * 8;
      gload_lds16(Xh  + ao, Ah + ld);
      gload_lds16(Xl  + ao, Al + ld);
      gload_lds16(YBh + bo, Bh + ld);
      gload_lds16(YBl + bo, Bl + ld);
    }
    asm volatile("s_waitcnt vmcnt(0)");
    __syncthreads();

    f16x8 ah[4], al[4], bh[4], bl[4];
    #pragma unroll
    for (int mi = 0; mi < 4; ++mi) {
      int off = (wm * 64 + mi * 16 + l15) * 32 + lhi * 8;
      ah[mi] = *reinterpret_cast<const f16x8*>(Ah + off);
      al[mi] = *reinterpret_cast<const f16x8*>(Al + off);
    }
    #pragma unroll
    for (int ni = 0; ni < 4; ++ni) {
      int off = (wn * 64 + ni * 16 + l15) * 32 + lhi * 8;
      bh[ni] = *reinterpret_cast<const f16x8*>(Bh + off);
      bl[ni] = *reinterpret_cast<const f16x8*>(Bl + off);
    }
    #pragma unroll
    for (int mi = 0; mi < 4; ++mi)
      #pragma unroll
      for (int ni = 0; ni < 4; ++ni) {
        acc[mi][ni] = __builtin_amdgcn_mfma_f32_16x16x32_f16(ah[mi], bh[ni], acc[mi][ni], 0, 0, 0);
        acc[mi][ni] = __builtin_amdgcn_mfma_f32_16x16x32_f16(ah[mi], bl[ni], acc[mi][ni], 0, 0, 0);
        acc[mi][ni] = __builtin_amdgcn_mfma_f32_16x16x32_f16(al[mi], bh[ni], acc[mi][ni], 0, 0, 0);
      }
    __syncthreads();
  }

  // C/D layout: col = lane&15, row = (lane>>4)*4 + r   [m89-verified]
  #pragma unroll
  for (int mi = 0; mi < 4; ++mi)
    #pragma unroll
    for (int ni = 0; ni < 4; ++ni) {
      int col = cf + wn * 64 + ni * 16 + l15;
      #pragma unroll
      for (int r = 0; r < 4; ++r) {
        int rw = rfLocal + wm * 64 + mi * 16 + lhi * 4 + r;
        S[(size_t)rw * NPTS + col] = acc[mi][ni][r];
      }
    }
}

// ---------- K3: per-row max + sparse candidate softmax/gather ----------
__global__ __launch_bounds__(256) void row_kernel(
    const float* __restrict__ Sp, const float* __restrict__ Sn,
    const float* __restrict__ bbp, const float* __restrict__ bbn,
    const float* __restrict__ ypos, const float* __restrict__ yneg,
    const float* __restrict__ accums, float* __restrict__ parts,
    float* __restrict__ Vout, int rowBase)
{
  __shared__ int   jlist[CAND_MAX];
  __shared__ float dulist[CAND_MAX];
  __shared__ float we0[CAND_MAX];
  __shared__ float we1[CAND_MAX];
  __shared__ float we2[CAND_MAX];
  __shared__ int   cnt;
  __shared__ float red[4];

  const int tid = threadIdx.x;
  const int local = blockIdx.x;
  const int row = rowBase + local;

  const float scalesq = accums[0] * (1.0f / (2.0f * NPTS * DIM)) + 1e-8f;
  const float L2E = 1.4426950408889634f;
  const float c0 = L2E / (scalesq * 0.02f);
  const float c1 = L2E / (scalesq * 0.05f);
  const float c2 = L2E / (scalesq * 0.2f);
  const float thr = 30.0f * scalesq * 0.2f;

  float V0 = 0.f, V1 = 0.f, V2 = 0.f;

  for (int side = 0; side < 2; ++side) {
    const float* S  = side ? Sn : Sp;
    const float* bb = side ? bbn : bbp;
    const float* y  = side ? yneg : ypos;
    const float sgn = side ? -1.f : 1.f;

    float uv[16];
    float mx = -3.0e38f;
    const float* Srow = S + (size_t)local * NPTS + tid * 16;
    const float* bbt  = bb + tid * 16;
    #pragma unroll
    for (int q = 0; q < 4; ++q) {
      float4 s4 = *reinterpret_cast<const float4*>(Srow + q * 4);
      float4 b4 = *reinterpret_cast<const float4*>(bbt + q * 4);
      uv[q * 4 + 0] = 2.0f * s4.x - b4.x;
      uv[q * 4 + 1] = 2.0f * s4.y - b4.y;
      uv[q * 4 + 2] = 2.0f * s4.z - b4.z;
      uv[q * 4 + 3] = 2.0f * s4.w - b4.w;
      mx = fmaxf(mx, fmaxf(fmaxf(uv[q*4], uv[q*4+1]), fmaxf(uv[q*4+2], uv[q*4+3])));
    }
    float m = blk_max(mx, red);

    if (tid == 0) cnt = 0;
    __syncthreads();
    #pragma unroll
    for (int e = 0; e < 16; ++e) {
      float du = uv[e] - m;
      if (du > -thr) {
        int idx = atomicAdd(&cnt, 1);
        if (idx < CAND_MAX) { jlist[idx] = tid * 16 + e; dulist[idx] = du; }
      }
    }
    __syncthreads();
    int nc = min(cnt, CAND_MAX);

    for (int ci = tid; ci < nc; ci += 256) {
      float du = dulist[ci];
      we0[ci] = exp2fast(du * c0);
      we1[ci] = exp2fast(du * c1);
      we2[ci] = exp2fast(du * c2);
    }
    __syncthreads();

    float p0 = 0.f, p1 = 0.f, p2 = 0.f;
    for (int ci = 0; ci < nc; ++ci) { p0 += we0[ci]; p1 += we1[ci]; p2 += we2[ci]; }
    float il0 = sgn / p0, il1 = sgn / p1, il2 = sgn / p2;

    int ci = 0;
    for (; ci + 4 <= nc; ci += 4) {
      float yv[4];
      int jj[4];
      #pragma unroll
      for (int q = 0; q < 4; ++q) jj[q] = jlist[ci + q];
      #pragma unroll
      for (int q = 0; q < 4; ++q) yv[q] = y[(size_t)jj[q] * DIM + tid];
      #pragma unroll
      for (int q = 0; q < 4; ++q) {
        V0 += we0[ci + q] * il0 * yv[q];
        V1 += we1[ci + q] * il1 * yv[q];
        V2 += we2[ci + q] * il2 * yv[q];
      }
    }
    for (; ci < nc; ++ci) {
      float yv = y[(size_t)jlist[ci] * DIM + tid];
      V0 += we0[ci] * il0 * yv;
      V1 += we1[ci] * il1 * yv;
      V2 += we2[ci] * il2 * yv;
    }
    __syncthreads();
  }

  float vr = (V0 + V1 + V2) * (1.0f / 3.0f);
  Vout[(size_t)row * DIM + tid] = vr;

  float s0 = blk_sum(V0 * V0, red);
  float s1 = blk_sum(V1 * V1, red);
  float s2 = blk_sum(V2 * V2, red);
  float sr = blk_sum(vr * vr, red);
  if (tid == 0) {
    parts[row]            = sr;
    parts[NPTS + row]     = s0;
    parts[2 * NPTS + row] = s1;
    parts[3 * NPTS + row] = s2;
  }
}

// ---------- reduce_parts: accums[1..4] = row-sums of parts ----------
__global__ __launch_bounds__(256) void reduce_parts(
    const float* __restrict__ parts, float* __restrict__ accums)
{
  __shared__ float red[4];
  int tid = threadIdx.x;
  #pragma unroll
  for (int a = 0; a < 4; ++a) {
    float s = 0.f;
    for (int k = tid; k < NPTS; k += 256) s += parts[a * NPTS + k];
    s = blk_sum(s, red);
    if (tid == 0) accums[1 + a] = s;
  }
}

// ---------- K4: finalize scalars + scale V by 1/lambda ----------
__global__ __launch_bounds__(256) void final_kernel(
    const float* __restrict__ accums, float* __restrict__ out)
{
  float raw  = accums[1] * (1.0f / NPTS);
  float lam2 = raw * (1.0f / DIM) + 1e-8f;
  float lam  = sqrtf(lam2);
  float inv  = 1.0f / lam;
  size_t idx = (size_t)blockIdx.x * 256 + threadIdx.x;
  out[7 + idx] *= inv;
  if (blockIdx.x == 0 && threadIdx.x == 0) {
    float drift = raw / lam2;
    out[0] = drift * (1.0f / DIM);
    out[1] = drift;
    out[2] = raw;
    out[3] = lam;
    out[4] = accums[2] * (1.0f / NPTS);
    out[5] = accums[3] * (1.0f / NPTS);
    out[6] = accums[4] * (1.0f / NPTS);
  }
}

extern "C" void kernel_launch(void* const* d_in, const int* in_sizes, int n_in,
                              void* d_out, int out_size, void* d_ws, size_t ws_size,
                              hipStream_t stream)
{
  (void)in_sizes; (void)n_in; (void)out_size;
  const float* x    = (const float*)d_in[0];
  const float* ypos = (const float*)d_in[1];
  const float* yneg = (const float*)d_in[2];
  float* out = (float*)d_out;
  char* ws = (char*)d_ws;

  // ws: [accums 256B | bbp 16K | bbn 16K | parts 64K | splits 12M | S chunks]
  float* accums = (float*)ws;
  float* bbp    = (float*)(ws + 256);
  float* bbn    = (float*)(ws + 16640);
  float* parts  = (float*)(ws + 33024);
  const size_t NM = (size_t)NPTS * DIM;
  f16* xh  = (f16*)(ws + 98560);
  f16* xl  = xh + NM;
  f16* yph = xh + 2 * NM;
  f16* ypl = xh + 3 * NM;
  f16* ynh = xh + 4 * NM;
  f16* ynl = xh + 5 * NM;
  size_t fixedBytes = 98560 + 6 * NM * sizeof(f16);
  float* Sbase = (float*)(ws + fixedBytes);
  size_t avail = ws_size > fixedBytes ? ws_size - fixedBytes : 0;

  int R = 128;
  if      (avail >= 2ull * 4096 * NPTS * 4) R = 4096;
  else if (avail >= 2ull * 2048 * NPTS * 4) R = 2048;
  else if (avail >= 2ull * 1024 * NPTS * 4) R = 1024;
  else if (avail >= 2ull * 512  * NPTS * 4) R = 512;
  else if (avail >= 2ull * 256  * NPTS * 4) R = 256;
  float* Sp = Sbase;
  float* Sn = Sbase + (size_t)R * NPTS;

  split_kernel<<<NPTS / 4, 256, 0, stream>>>(x,    xh,  xl,  nullptr);
  split_kernel<<<NPTS / 4, 256, 0, stream>>>(ypos, yph, ypl, bbp);
  split_kernel<<<NPTS / 4, 256, 0, stream>>>(yneg, ynh, ynl, bbn);
  reduce_ss<<<1, 256, 0, stream>>>(bbp, bbn, accums);

  for (int base = 0; base < NPTS; base += R) {
    dim3 g(R / 128, NPTS / 128, 2);
    gemm_kernel<<<g, 256, 0, stream>>>(xh, xl, yph, ypl, ynh, ynl, Sp, Sn, base);
    row_kernel<<<R, 256, 0, stream>>>(Sp, Sn, bbp, bbn, ypos, yneg, accums, parts, out + 7, base);
  }
  reduce_parts<<<1, 256, 0, stream>>>(parts, accums);
  final_kernel<<<NPTS, 256, 0, stream>>>(accums, out);
}

// Round 4
// 116.880 us; speedup vs baseline: 4.0274x; 1.1649x over previous
//
#include <hip/hip_runtime.h>

#define NPTS 4096
#define DIM  256
#define TILES 32
#define CAND 128

typedef _Float16 f16;
typedef unsigned short u16;
typedef __attribute__((ext_vector_type(8))) short bf16x8;
typedef __attribute__((ext_vector_type(4))) float f32x4;
typedef __attribute__((ext_vector_type(4))) unsigned short u16x4;

__device__ __forceinline__ float exp2fast(float x) {
  float r;
  asm("v_exp_f32 %0, %1" : "=v"(r) : "v"(x));
  return r;
}

__device__ __forceinline__ void gload_lds16(const void* g, void* l) {
  __builtin_amdgcn_global_load_lds((const __attribute__((address_space(1))) void*)g,
                                   (__attribute__((address_space(3))) void*)l, 16, 0, 0);
}

// ---------- block-wide reductions (256 threads = 4 waves) ----------
__device__ __forceinline__ float blk_max(float v, float* sh) {
  #pragma unroll
  for (int off = 32; off; off >>= 1) v = fmaxf(v, __shfl_down(v, off));
  int lane = threadIdx.x & 63, w = threadIdx.x >> 6;
  __syncthreads();
  if (lane == 0) sh[w] = v;
  __syncthreads();
  return fmaxf(fmaxf(sh[0], sh[1]), fmaxf(sh[2], sh[3]));
}

__device__ __forceinline__ float blk_sum(float v, float* sh) {
  #pragma unroll
  for (int off = 32; off; off >>= 1) v += __shfl_down(v, off);
  int lane = threadIdx.x & 63, w = threadIdx.x >> 6;
  __syncthreads();
  if (lane == 0) sh[w] = v;
  __syncthreads();
  return sh[0] + sh[1] + sh[2] + sh[3];
}

// ---------- K1: bf16 round + row sumsq ----------
__global__ __launch_bounds__(256) void split_kernel(
    const float* __restrict__ src, u16* __restrict__ dst, float* __restrict__ bb)
{
  int lane = threadIdx.x & 63;
  int wave = threadIdx.x >> 6;
  int row  = blockIdx.x * 4 + wave;
  const float4 v = *reinterpret_cast<const float4*>(src + (size_t)row * DIM + lane * 4);
  float xs[4] = {v.x, v.y, v.z, v.w};
  u16x4 h;
  float ss = 0.f;
  #pragma unroll
  for (int e = 0; e < 4; ++e) {
    unsigned b = __float_as_uint(xs[e]);
    h[e] = (u16)((b + 0x7fffu + ((b >> 16) & 1u)) >> 16);   // bf16 RTNE
    ss += xs[e] * xs[e];
  }
  *reinterpret_cast<u16x4*>(dst + (size_t)row * DIM + lane * 4) = h;
  if (bb) {
    #pragma unroll
    for (int off = 32; off; off >>= 1) ss += __shfl_down(ss, off);
    if (lane == 0) bb[row] = ss;
  }
}

// ---------- reduce_ss: accums[0] = sum(bbp) + sum(bbn) ----------
__global__ __launch_bounds__(256) void reduce_ss(
    const float* __restrict__ bbp, const float* __restrict__ bbn, float* __restrict__ accums)
{
  __shared__ float red[4];
  int tid = threadIdx.x;
  float s = 0.f;
  for (int k = tid; k < NPTS; k += 256) s += bbp[k] + bbn[k];
  s = blk_sum(s, red);
  if (tid == 0) accums[0] = s;
}

// ---------- K2: bf16 GEMM tile 128x128, BK=64; epilogue stores f16 u + per-tile row max ----------
__global__ __launch_bounds__(256) void gemm_kernel(
    const u16* __restrict__ Xb, const u16* __restrict__ Ypb, const u16* __restrict__ Ynb,
    const float* __restrict__ bbp, const float* __restrict__ bbn,
    const float* __restrict__ accums,
    f16* __restrict__ Up, f16* __restrict__ Un,
    float* __restrict__ Mp, float* __restrict__ Mn, int rowBase)
{
  __shared__ u16 Ah[128 * 64];
  __shared__ u16 Bh[128 * 64];
  __shared__ float Mred[2][128];

  const u16* Yb; const float* bbv; f16* U; float* Mg;
  if (blockIdx.z == 0) { Yb = Ypb; bbv = bbp; U = Up; Mg = Mp; }
  else                 { Yb = Ynb; bbv = bbn; U = Un; Mg = Mn; }

  const int tid  = threadIdx.x;
  const int lane = tid & 63;
  const int wave = tid >> 6;
  const int wm = wave >> 1, wn = wave & 1;
  const int l15 = lane & 15, lhi = lane >> 4;

  const int rfLocal = blockIdx.x * 128;
  const int rfGlob  = rowBase + rfLocal;
  const int cf      = blockIdx.y * 128;

  const int sr = lane >> 3;        // row within 8-row staging group
  const int ce = (lane & 7) * 8;   // element chunk (8 bf16 = 16B)

  f32x4 acc[4][4] = {};

  #pragma unroll 1
  for (int ks = 0; ks < 4; ++ks) {
    #pragma unroll
    for (int i = 0; i < 4; ++i) {
      int r = wave * 32 + i * 8 + sr;
      gload_lds16(Xb + (size_t)(rfGlob + r) * DIM + ks * 64 + ce, Ah + r * 64 + ce);
      gload_lds16(Yb + (size_t)(cf     + r) * DIM + ks * 64 + ce, Bh + r * 64 + ce);
    }
    asm volatile("s_waitcnt vmcnt(0)");
    __syncthreads();

    bf16x8 a[2][4], b[2][4];
    #pragma unroll
    for (int k2 = 0; k2 < 2; ++k2) {
      #pragma unroll
      for (int mi = 0; mi < 4; ++mi)
        a[k2][mi] = *reinterpret_cast<const bf16x8*>(Ah + (wm * 64 + mi * 16 + l15) * 64 + k2 * 32 + lhi * 8);
      #pragma unroll
      for (int ni = 0; ni < 4; ++ni)
        b[k2][ni] = *reinterpret_cast<const bf16x8*>(Bh + (wn * 64 + ni * 16 + l15) * 64 + k2 * 32 + lhi * 8);
    }
    #pragma unroll
    for (int k2 = 0; k2 < 2; ++k2)
      #pragma unroll
      for (int mi = 0; mi < 4; ++mi)
        #pragma unroll
        for (int ni = 0; ni < 4; ++ni)
          acc[mi][ni] = __builtin_amdgcn_mfma_f32_16x16x32_bf16(a[k2][mi], b[k2][ni], acc[mi][ni], 0, 0, 0);
    __syncthreads();
  }

  // ---- epilogue: u = 2*acc - bb[col] + SHIFT -> f16 store + per-row max ----
  const float SHIFT = accums[0] * (1.0f / (2.0f * NPTS));
  float bbc[4];
  #pragma unroll
  for (int ni = 0; ni < 4; ++ni) bbc[ni] = bbv[cf + wn * 64 + ni * 16 + l15];

  float um[4][4];
  #pragma unroll
  for (int mi = 0; mi < 4; ++mi)
    #pragma unroll
    for (int r = 0; r < 4; ++r) um[mi][r] = -3.0e38f;

  #pragma unroll
  for (int mi = 0; mi < 4; ++mi)
    #pragma unroll
    for (int ni = 0; ni < 4; ++ni) {
      int col = cf + wn * 64 + ni * 16 + l15;
      #pragma unroll
      for (int r = 0; r < 4; ++r) {
        float u = 2.0f * acc[mi][ni][r] - bbc[ni] + SHIFT;
        int rw = rfLocal + wm * 64 + mi * 16 + lhi * 4 + r;
        U[(size_t)rw * NPTS + col] = (f16)u;
        um[mi][r] = fmaxf(um[mi][r], u);
      }
    }

  // reduce row max across the 16 l15 lanes (xor<16 stays in group)
  #pragma unroll
  for (int mi = 0; mi < 4; ++mi)
    #pragma unroll
    for (int r = 0; r < 4; ++r) {
      float v = um[mi][r];
      #pragma unroll
      for (int off = 1; off < 16; off <<= 1) v = fmaxf(v, __shfl_xor(v, off));
      um[mi][r] = v;
    }
  if (l15 == 0) {
    #pragma unroll
    for (int mi = 0; mi < 4; ++mi)
      #pragma unroll
      for (int r = 0; r < 4; ++r)
        Mred[wn][wm * 64 + mi * 16 + lhi * 4 + r] = um[mi][r];
  }
  __syncthreads();
  if (tid < 128)
    Mg[(size_t)(rfLocal + tid) * TILES + blockIdx.y] = fmaxf(Mred[0][tid], Mred[1][tid]);
}

// ---------- K3: tile-pruned candidate softmax with exact f32 recompute ----------
__global__ __launch_bounds__(256) void row_kernel(
    const f16* __restrict__ Up, const f16* __restrict__ Un,
    const float* __restrict__ Mp, const float* __restrict__ Mn,
    const float* __restrict__ bbp, const float* __restrict__ bbn,
    const float* __restrict__ x,
    const float* __restrict__ ypos, const float* __restrict__ yneg,
    const float* __restrict__ accums, float* __restrict__ parts,
    float* __restrict__ Vout, int rowBase)
{
  __shared__ int   jlist[CAND];
  __shared__ float ulist[CAND];
  __shared__ float wl0[CAND], wl1[CAND], wl2[CAND];
  __shared__ int   tlist[TILES];
  __shared__ int   cnt, tcnt;
  __shared__ float red[4];

  const int tid = threadIdx.x;
  const int local = blockIdx.x;
  const int row = rowBase + local;
  const int lane = tid & 63, wave = tid >> 6;

  const float scalesq = accums[0] * (1.0f / (2.0f * NPTS * DIM)) + 1e-8f;
  const float L2E = 1.4426950408889634f;
  const float c0 = L2E / (scalesq * 0.02f);
  const float c1 = L2E / (scalesq * 0.05f);
  const float c2 = L2E / (scalesq * 0.2f);
  const float thr  = 30.0f * scalesq * 0.2f;
  const float thrP = thr + 2.5f * scalesq + 0.5f;   // margin for bf16/f16 error

  float V0 = 0.f, V1 = 0.f, V2 = 0.f;

  for (int side = 0; side < 2; ++side) {
    const f16*  U  = side ? Un  : Up;
    const float* M = side ? Mn  : Mp;
    const float* bb = side ? bbn : bbp;
    const float* y  = side ? yneg : ypos;
    const float sgn = side ? -1.f : 1.f;

    // global max from per-tile maxes
    float mv = (tid < TILES) ? M[(size_t)local * TILES + tid] : -3.0e38f;
    float m = blk_max(mv, red);

    if (tid == 0) { cnt = 0; tcnt = 0; }
    __syncthreads();
    if (tid < TILES && mv > m - thrP) {
      int t = atomicAdd(&tcnt, 1);
      tlist[t] = tid;
    }
    __syncthreads();
    int nt = tcnt;

    // scan kept tiles' stored u (f16, shifted domain)
    for (int ti = 0; ti < nt; ++ti) {
      int kt = tlist[ti];
      if (tid < 128) {
        float uv = (float)U[(size_t)local * NPTS + kt * 128 + tid];
        if (uv > m - thrP) {
          int idx = atomicAdd(&cnt, 1);
          if (idx < CAND) jlist[idx] = kt * 128 + tid;
        }
      }
    }
    __syncthreads();
    int nc = min(cnt, CAND);

    // exact f32 dot per candidate: one wave per candidate
    for (int ci = wave; ci < nc; ci += 4) {
      int j = jlist[ci];
      float4 xv = *reinterpret_cast<const float4*>(x + (size_t)row * DIM + lane * 4);
      float4 yv = *reinterpret_cast<const float4*>(y + (size_t)j   * DIM + lane * 4);
      float d = xv.x * yv.x + xv.y * yv.y + xv.z * yv.z + xv.w * yv.w;
      #pragma unroll
      for (int off = 32; off; off >>= 1) d += __shfl_down(d, off);
      if (lane == 0) ulist[ci] = 2.0f * d - bb[j];
    }
    __syncthreads();

    // exact max over candidates
    float um = (tid < nc) ? ulist[tid] : -3.0e38f;
    float me = blk_max(um, red);

    if (tid < nc) {
      float du = ulist[tid] - me;
      wl0[tid] = exp2fast(du * c0);
      wl1[tid] = exp2fast(du * c1);
      wl2[tid] = exp2fast(du * c2);
    }
    __syncthreads();

    float p0 = 0.f, p1 = 0.f, p2 = 0.f;
    for (int ci = 0; ci < nc; ++ci) { p0 += wl0[ci]; p1 += wl1[ci]; p2 += wl2[ci]; }
    float il0 = sgn / p0, il1 = sgn / p1, il2 = sgn / p2;

    // V gather: thread owns output dim tid
    for (int ci = 0; ci < nc; ++ci) {
      float yv = y[(size_t)jlist[ci] * DIM + tid];
      V0 += wl0[ci] * il0 * yv;
      V1 += wl1[ci] * il1 * yv;
      V2 += wl2[ci] * il2 * yv;
    }
    __syncthreads();
  }

  float vr = (V0 + V1 + V2) * (1.0f / 3.0f);
  Vout[(size_t)row * DIM + tid] = vr;

  float s0 = blk_sum(V0 * V0, red);
  float s1 = blk_sum(V1 * V1, red);
  float s2 = blk_sum(V2 * V2, red);
  float sr = blk_sum(vr * vr, red);
  if (tid == 0) {
    parts[row]            = sr;
    parts[NPTS + row]     = s0;
    parts[2 * NPTS + row] = s1;
    parts[3 * NPTS + row] = s2;
  }
}

// ---------- reduce_parts ----------
__global__ __launch_bounds__(256) void reduce_parts(
    const float* __restrict__ parts, float* __restrict__ accums)
{
  __shared__ float red[4];
  int tid = threadIdx.x;
  #pragma unroll
  for (int a = 0; a < 4; ++a) {
    float s = 0.f;
    for (int k = tid; k < NPTS; k += 256) s += parts[a * NPTS + k];
    s = blk_sum(s, red);
    if (tid == 0) accums[1 + a] = s;
  }
}

// ---------- K4: finalize ----------
__global__ __launch_bounds__(256) void final_kernel(
    const float* __restrict__ accums, float* __restrict__ out)
{
  float raw  = accums[1] * (1.0f / NPTS);
  float lam2 = raw * (1.0f / DIM) + 1e-8f;
  float lam  = sqrtf(lam2);
  float inv  = 1.0f / lam;
  size_t idx = (size_t)blockIdx.x * 256 + threadIdx.x;
  out[7 + idx] *= inv;
  if (blockIdx.x == 0 && threadIdx.x == 0) {
    float drift = raw / lam2;
    out[0] = drift * (1.0f / DIM);
    out[1] = drift;
    out[2] = raw;
    out[3] = lam;
    out[4] = accums[2] * (1.0f / NPTS);
    out[5] = accums[3] * (1.0f / NPTS);
    out[6] = accums[4] * (1.0f / NPTS);
  }
}

extern "C" void kernel_launch(void* const* d_in, const int* in_sizes, int n_in,
                              void* d_out, int out_size, void* d_ws, size_t ws_size,
                              hipStream_t stream)
{
  (void)in_sizes; (void)n_in; (void)out_size;
  const float* x    = (const float*)d_in[0];
  const float* ypos = (const float*)d_in[1];
  const float* yneg = (const float*)d_in[2];
  float* out = (float*)d_out;
  char* ws = (char*)d_ws;

  // ws: accums | bbp | bbn | parts | Mp | Mn | xb | ypb | ynb | U chunks
  float* accums = (float*)ws;
  float* bbp    = (float*)(ws + 256);
  float* bbn    = (float*)(ws + 16640);
  float* parts  = (float*)(ws + 33024);
  float* Mp     = (float*)(ws + 98560);
  float* Mn     = (float*)(ws + 98560 + 524288);
  u16* xb  = (u16*)(ws + 98560 + 2 * 524288);
  u16* ypb = xb + (size_t)NPTS * DIM;
  u16* ynb = xb + 2 * (size_t)NPTS * DIM;
  size_t fixedBytes = 98560 + 2 * 524288 + 3ull * NPTS * DIM * 2;
  f16* Ubase = (f16*)(ws + fixedBytes);
  size_t avail = ws_size > fixedBytes ? ws_size - fixedBytes : 0;

  int R = 128;
  if      (avail >= 2ull * 4096 * NPTS * 2) R = 4096;
  else if (avail >= 2ull * 2048 * NPTS * 2) R = 2048;
  else if (avail >= 2ull * 1024 * NPTS * 2) R = 1024;
  else if (avail >= 2ull * 512  * NPTS * 2) R = 512;
  else if (avail >= 2ull * 256  * NPTS * 2) R = 256;
  f16* Up = Ubase;
  f16* Un = Ubase + (size_t)R * NPTS;

  split_kernel<<<NPTS / 4, 256, 0, stream>>>(x,    xb,  nullptr);
  split_kernel<<<NPTS / 4, 256, 0, stream>>>(ypos, ypb, bbp);
  split_kernel<<<NPTS / 4, 256, 0, stream>>>(yneg, ynb, bbn);
  reduce_ss<<<1, 256, 0, stream>>>(bbp, bbn, accums);

  for (int base = 0; base < NPTS; base += R) {
    dim3 g(R / 128, NPTS / 128, 2);
    gemm_kernel<<<g, 256, 0, stream>>>(xb, ypb, ynb, bbp, bbn, accums, Up, Un, Mp, Mn, base);
    row_kernel<<<R, 256, 0, stream>>>(Up, Un, Mp, Mn, bbp, bbn, x, ypos, yneg,
                                      accums, parts, out + 7, base);
  }
  reduce_parts<<<1, 256, 0, stream>>>(parts, accums);
  final_kernel<<<NPTS, 256, 0, stream>>>(accums, out);
}

// Round 5
// 103.760 us; speedup vs baseline: 4.5367x; 1.1264x over previous
//
#include <hip/hip_runtime.h>

#define NPTS 4096
#define DIM  256
#define TILES 32
#define CAND 128

typedef _Float16 f16;
typedef unsigned short u16;
typedef __attribute__((ext_vector_type(4))) _Float16 f16x4;
typedef __attribute__((ext_vector_type(8))) short bf16x8;
typedef __attribute__((ext_vector_type(4))) float f32x4;
typedef __attribute__((ext_vector_type(4))) unsigned short u16x4;

__device__ __forceinline__ float exp2fast(float x) {
  float r;
  asm("v_exp_f32 %0, %1" : "=v"(r) : "v"(x));
  return r;
}

__device__ __forceinline__ void gload_lds16(const void* g, void* l) {
  __builtin_amdgcn_global_load_lds((const __attribute__((address_space(1))) void*)g,
                                   (__attribute__((address_space(3))) void*)l, 16, 0, 0);
}

// ---------- block-wide reductions (256 threads = 4 waves) ----------
__device__ __forceinline__ float blk_max(float v, float* sh) {
  #pragma unroll
  for (int off = 32; off; off >>= 1) v = fmaxf(v, __shfl_down(v, off));
  int lane = threadIdx.x & 63, w = threadIdx.x >> 6;
  __syncthreads();
  if (lane == 0) sh[w] = v;
  __syncthreads();
  return fmaxf(fmaxf(sh[0], sh[1]), fmaxf(sh[2], sh[3]));
}

__device__ __forceinline__ float blk_sum(float v, float* sh) {
  #pragma unroll
  for (int off = 32; off; off >>= 1) v += __shfl_down(v, off);
  int lane = threadIdx.x & 63, w = threadIdx.x >> 6;
  __syncthreads();
  if (lane == 0) sh[w] = v;
  __syncthreads();
  return sh[0] + sh[1] + sh[2] + sh[3];
}

// ---------- K1: bf16 round + row sumsq for all three inputs (grid.y selects) ----------
__global__ __launch_bounds__(256) void split3_kernel(
    const float* __restrict__ x, const float* __restrict__ yp, const float* __restrict__ yn,
    u16* __restrict__ xb, u16* __restrict__ ypb, u16* __restrict__ ynb,
    float* __restrict__ bbp, float* __restrict__ bbn)
{
  const float* src; u16* dst; float* bb;
  if      (blockIdx.y == 0) { src = x;  dst = xb;  bb = nullptr; }
  else if (blockIdx.y == 1) { src = yp; dst = ypb; bb = bbp; }
  else                      { src = yn; dst = ynb; bb = bbn; }

  int lane = threadIdx.x & 63;
  int wave = threadIdx.x >> 6;
  int row  = blockIdx.x * 4 + wave;
  const float4 v = *reinterpret_cast<const float4*>(src + (size_t)row * DIM + lane * 4);
  float xs[4] = {v.x, v.y, v.z, v.w};
  u16x4 h;
  float ss = 0.f;
  #pragma unroll
  for (int e = 0; e < 4; ++e) {
    unsigned b = __float_as_uint(xs[e]);
    h[e] = (u16)((b + 0x7fffu + ((b >> 16) & 1u)) >> 16);   // bf16 RTNE
    ss += xs[e] * xs[e];
  }
  *reinterpret_cast<u16x4*>(dst + (size_t)row * DIM + lane * 4) = h;
  if (bb) {
    #pragma unroll
    for (int off = 32; off; off >>= 1) ss += __shfl_down(ss, off);
    if (lane == 0) bb[row] = ss;
  }
}

// ---------- reduce_ss: accums[0] = sum(bbp) + sum(bbn) ----------
__global__ __launch_bounds__(256) void reduce_ss(
    const float* __restrict__ bbp, const float* __restrict__ bbn, float* __restrict__ accums)
{
  __shared__ float red[4];
  int tid = threadIdx.x;
  float s = 0.f;
  for (int k = tid; k < NPTS; k += 256) s += bbp[k] + bbn[k];
  s = blk_sum(s, red);
  if (tid == 0) accums[0] = s;
}

// ---------- K2: bf16 GEMM 128x128, BK=64, XOR-swizzled LDS, packed permuted U store ----------
__global__ __launch_bounds__(256) void gemm_kernel(
    const u16* __restrict__ Xb, const u16* __restrict__ Ypb, const u16* __restrict__ Ynb,
    const float* __restrict__ bbp, const float* __restrict__ bbn,
    const float* __restrict__ accums,
    f16* __restrict__ Up, f16* __restrict__ Un,
    float* __restrict__ Mp, float* __restrict__ Mn, int rowBase)
{
  __shared__ u16 Ah[128 * 64];
  __shared__ u16 Bh[128 * 64];
  __shared__ float Mred[2][128];

  const u16* Yb; const float* bbv; f16* U; float* Mg;
  if (blockIdx.z == 0) { Yb = Ypb; bbv = bbp; U = Up; Mg = Mp; }
  else                 { Yb = Ynb; bbv = bbn; U = Un; Mg = Mn; }

  const int tid  = threadIdx.x;
  const int lane = tid & 63;
  const int wave = tid >> 6;
  const int wm = wave >> 1, wn = wave & 1;
  const int l15 = lane & 15, lhi = lane >> 4;

  const int rfLocal = blockIdx.x * 128;
  const int rfGlob  = rowBase + rfLocal;
  const int cf      = blockIdx.y * 128;

  // staging: row r = wave*32 + i*8 + sr; LDS dest linear (base + lane*16B);
  // global source chunk pre-swizzled with (r&7) so reads can XOR-deswizzle.
  const int sr = lane >> 3;                       // 0..7  (== r&7)
  const int sc = lane & 7;                        // physical chunk 0..7
  const int gc = (sc ^ sr) * 8;                   // pre-swizzled source element

  f32x4 acc[4][4] = {};

  #pragma unroll 1
  for (int ks = 0; ks < 4; ++ks) {
    #pragma unroll
    for (int i = 0; i < 4; ++i) {
      int r = wave * 32 + i * 8 + sr;
      gload_lds16(Xb + (size_t)(rfGlob + r) * DIM + ks * 64 + gc, Ah + r * 64 + sc * 8);
      gload_lds16(Yb + (size_t)(cf     + r) * DIM + ks * 64 + gc, Bh + r * 64 + sc * 8);
    }
    asm volatile("s_waitcnt vmcnt(0)");
    __syncthreads();

    bf16x8 a[2][4], b[2][4];
    #pragma unroll
    for (int k2 = 0; k2 < 2; ++k2) {
      #pragma unroll
      for (int mi = 0; mi < 4; ++mi) {
        int R = wm * 64 + mi * 16 + l15;
        int pc = (k2 * 4 + lhi) ^ (l15 & 7);
        a[k2][mi] = *reinterpret_cast<const bf16x8*>(Ah + R * 64 + pc * 8);
      }
      #pragma unroll
      for (int ni = 0; ni < 4; ++ni) {
        int R = wn * 64 + ni * 16 + l15;
        int pc = (k2 * 4 + lhi) ^ (l15 & 7);
        b[k2][ni] = *reinterpret_cast<const bf16x8*>(Bh + R * 64 + pc * 8);
      }
    }
    #pragma unroll
    for (int k2 = 0; k2 < 2; ++k2)
      #pragma unroll
      for (int mi = 0; mi < 4; ++mi)
        #pragma unroll
        for (int ni = 0; ni < 4; ++ni)
          acc[mi][ni] = __builtin_amdgcn_mfma_f32_16x16x32_bf16(a[k2][mi], b[k2][ni], acc[mi][ni], 0, 0, 0);
    __syncthreads();
  }

  // ---- epilogue: u = 2*acc - bb[col] + SHIFT; packed 8B store at permuted slot ----
  // physical slot q = wn*64 + l15*4 + ni  <->  logical col offset = wn*64 + ni*16 + l15
  const float SHIFT = accums[0] * (1.0f / (2.0f * NPTS));
  float bbc[4];
  #pragma unroll
  for (int ni = 0; ni < 4; ++ni) bbc[ni] = bbv[cf + wn * 64 + ni * 16 + l15];

  float um[4][4];
  #pragma unroll
  for (int mi = 0; mi < 4; ++mi)
    #pragma unroll
    for (int r = 0; r < 4; ++r) {
      f16x4 pack;
      float mxv = -3.0e38f;
      #pragma unroll
      for (int ni = 0; ni < 4; ++ni) {
        float u = 2.0f * acc[mi][ni][r] - bbc[ni] + SHIFT;
        pack[ni] = (f16)u;
        mxv = fmaxf(mxv, u);
      }
      um[mi][r] = mxv;
      int rw = rfLocal + wm * 64 + mi * 16 + lhi * 4 + r;
      *reinterpret_cast<f16x4*>(U + (size_t)rw * NPTS + cf + wn * 64 + l15 * 4) = pack;
    }

  // reduce row max across the 16 l15 lanes (xor<16 stays in group)
  #pragma unroll
  for (int mi = 0; mi < 4; ++mi)
    #pragma unroll
    for (int r = 0; r < 4; ++r) {
      float v = um[mi][r];
      #pragma unroll
      for (int off = 1; off < 16; off <<= 1) v = fmaxf(v, __shfl_xor(v, off));
      um[mi][r] = v;
    }
  if (l15 == 0) {
    #pragma unroll
    for (int mi = 0; mi < 4; ++mi)
      #pragma unroll
      for (int r = 0; r < 4; ++r)
        Mred[wn][wm * 64 + mi * 16 + lhi * 4 + r] = um[mi][r];
  }
  __syncthreads();
  if (tid < 128)
    Mg[(size_t)(rfLocal + tid) * TILES + blockIdx.y] = fmaxf(Mred[0][tid], Mred[1][tid]);
}

// ---------- K3: tile-pruned candidate softmax with exact f32 recompute ----------
__global__ __launch_bounds__(256) void row_kernel(
    const f16* __restrict__ Up, const f16* __restrict__ Un,
    const float* __restrict__ Mp, const float* __restrict__ Mn,
    const float* __restrict__ bbp, const float* __restrict__ bbn,
    const float* __restrict__ x,
    const float* __restrict__ ypos, const float* __restrict__ yneg,
    const float* __restrict__ accums, float* __restrict__ parts,
    float* __restrict__ Vout, int rowBase)
{
  __shared__ int   jlist[CAND];
  __shared__ float ulist[CAND];
  __shared__ float wl0[CAND], wl1[CAND], wl2[CAND];
  __shared__ int   tlist[TILES];
  __shared__ int   cnt, tcnt;
  __shared__ float red[4];

  const int tid = threadIdx.x;
  const int local = blockIdx.x;
  const int row = rowBase + local;
  const int lane = tid & 63, wave = tid >> 6;

  const float scalesq = accums[0] * (1.0f / (2.0f * NPTS * DIM)) + 1e-8f;
  const float L2E = 1.4426950408889634f;
  const float c0 = L2E / (scalesq * 0.02f);
  const float c1 = L2E / (scalesq * 0.05f);
  const float c2 = L2E / (scalesq * 0.2f);
  const float thr  = 30.0f * scalesq * 0.2f;
  const float thrP = thr + 2.5f * scalesq + 0.5f;   // margin for bf16/f16 error

  float V0 = 0.f, V1 = 0.f, V2 = 0.f;

  for (int side = 0; side < 2; ++side) {
    const f16*  U  = side ? Un  : Up;
    const float* M = side ? Mn  : Mp;
    const float* bb = side ? bbn : bbp;
    const float* y  = side ? yneg : ypos;
    const float sgn = side ? -1.f : 1.f;

    float mv = (tid < TILES) ? M[(size_t)local * TILES + tid] : -3.0e38f;
    float m = blk_max(mv, red);

    if (tid == 0) { cnt = 0; tcnt = 0; }
    __syncthreads();
    if (tid < TILES && mv > m - thrP) {
      int t = atomicAdd(&tcnt, 1);
      tlist[t] = tid;
    }
    __syncthreads();
    int nt = tcnt;

    // scan kept tiles' stored u (f16, permuted layout)
    for (int ti = 0; ti < nt; ++ti) {
      int kt = tlist[ti];
      if (tid < 128) {
        float uv = (float)U[(size_t)local * NPTS + kt * 128 + tid];
        if (uv > m - thrP) {
          int idx = atomicAdd(&cnt, 1);
          if (idx < CAND) {
            int q = tid;   // physical slot -> logical col
            jlist[idx] = kt * 128 + ((q >> 6) * 64 + (q & 3) * 16 + ((q >> 2) & 15));
          }
        }
      }
    }
    __syncthreads();
    int nc = min(cnt, CAND);

    // exact f32 dot per candidate: one wave per candidate
    for (int ci = wave; ci < nc; ci += 4) {
      int j = jlist[ci];
      float4 xv = *reinterpret_cast<const float4*>(x + (size_t)row * DIM + lane * 4);
      float4 yv = *reinterpret_cast<const float4*>(y + (size_t)j   * DIM + lane * 4);
      float d = xv.x * yv.x + xv.y * yv.y + xv.z * yv.z + xv.w * yv.w;
      #pragma unroll
      for (int off = 32; off; off >>= 1) d += __shfl_down(d, off);
      if (lane == 0) ulist[ci] = 2.0f * d - bb[j];
    }
    __syncthreads();

    float um = (tid < nc) ? ulist[tid] : -3.0e38f;
    float me = blk_max(um, red);

    if (tid < nc) {
      float du = ulist[tid] - me;
      wl0[tid] = exp2fast(du * c0);
      wl1[tid] = exp2fast(du * c1);
      wl2[tid] = exp2fast(du * c2);
    }
    __syncthreads();

    float p0 = 0.f, p1 = 0.f, p2 = 0.f;
    for (int ci = 0; ci < nc; ++ci) { p0 += wl0[ci]; p1 += wl1[ci]; p2 += wl2[ci]; }
    float il0 = sgn / p0, il1 = sgn / p1, il2 = sgn / p2;

    for (int ci = 0; ci < nc; ++ci) {
      float yv = y[(size_t)jlist[ci] * DIM + tid];
      V0 += wl0[ci] * il0 * yv;
      V1 += wl1[ci] * il1 * yv;
      V2 += wl2[ci] * il2 * yv;
    }
    __syncthreads();
  }

  float vr = (V0 + V1 + V2) * (1.0f / 3.0f);
  Vout[(size_t)row * DIM + tid] = vr;

  float s0 = blk_sum(V0 * V0, red);
  float s1 = blk_sum(V1 * V1, red);
  float s2 = blk_sum(V2 * V2, red);
  float sr = blk_sum(vr * vr, red);
  if (tid == 0) {
    parts[row]            = sr;
    parts[NPTS + row]     = s0;
    parts[2 * NPTS + row] = s1;
    parts[3 * NPTS + row] = s2;
  }
}

// ---------- reduce_parts ----------
__global__ __launch_bounds__(256) void reduce_parts(
    const float* __restrict__ parts, float* __restrict__ accums)
{
  __shared__ float red[4];
  int tid = threadIdx.x;
  #pragma unroll
  for (int a = 0; a < 4; ++a) {
    float s = 0.f;
    for (int k = tid; k < NPTS; k += 256) s += parts[a * NPTS + k];
    s = blk_sum(s, red);
    if (tid == 0) accums[1 + a] = s;
  }
}

// ---------- K4: finalize ----------
__global__ __launch_bounds__(256) void final_kernel(
    const float* __restrict__ accums, float* __restrict__ out)
{
  float raw  = accums[1] * (1.0f / NPTS);
  float lam2 = raw * (1.0f / DIM) + 1e-8f;
  float lam  = sqrtf(lam2);
  float inv  = 1.0f / lam;
  size_t idx = (size_t)blockIdx.x * 256 + threadIdx.x;
  out[7 + idx] *= inv;
  if (blockIdx.x == 0 && threadIdx.x == 0) {
    float drift = raw / lam2;
    out[0] = drift * (1.0f / DIM);
    out[1] = drift;
    out[2] = raw;
    out[3] = lam;
    out[4] = accums[2] * (1.0f / NPTS);
    out[5] = accums[3] * (1.0f / NPTS);
    out[6] = accums[4] * (1.0f / NPTS);
  }
}

extern "C" void kernel_launch(void* const* d_in, const int* in_sizes, int n_in,
                              void* d_out, int out_size, void* d_ws, size_t ws_size,
                              hipStream_t stream)
{
  (void)in_sizes; (void)n_in; (void)out_size;
  const float* x    = (const float*)d_in[0];
  const float* ypos = (const float*)d_in[1];
  const float* yneg = (const float*)d_in[2];
  float* out = (float*)d_out;
  char* ws = (char*)d_ws;

  float* accums = (float*)ws;
  float* bbp    = (float*)(ws + 256);
  float* bbn    = (float*)(ws + 16640);
  float* parts  = (float*)(ws + 33024);
  float* Mp     = (float*)(ws + 98560);
  float* Mn     = (float*)(ws + 98560 + 524288);
  u16* xb  = (u16*)(ws + 98560 + 2 * 524288);
  u16* ypb = xb + (size_t)NPTS * DIM;
  u16* ynb = xb + 2 * (size_t)NPTS * DIM;
  size_t fixedBytes = 98560 + 2 * 524288 + 3ull * NPTS * DIM * 2;
  f16* Ubase = (f16*)(ws + fixedBytes);
  size_t avail = ws_size > fixedBytes ? ws_size - fixedBytes : 0;

  int R = 128;
  if      (avail >= 2ull * 4096 * NPTS * 2) R = 4096;
  else if (avail >= 2ull * 2048 * NPTS * 2) R = 2048;
  else if (avail >= 2ull * 1024 * NPTS * 2) R = 1024;
  else if (avail >= 2ull * 512  * NPTS * 2) R = 512;
  else if (avail >= 2ull * 256  * NPTS * 2) R = 256;
  f16* Up = Ubase;
  f16* Un = Ubase + (size_t)R * NPTS;

  split3_kernel<<<dim3(NPTS / 4, 3), 256, 0, stream>>>(x, ypos, yneg, xb, ypb, ynb, bbp, bbn);
  reduce_ss<<<1, 256, 0, stream>>>(bbp, bbn, accums);

  for (int base = 0; base < NPTS; base += R) {
    dim3 g(R / 128, NPTS / 128, 2);
    gemm_kernel<<<g, 256, 0, stream>>>(xb, ypb, ynb, bbp, bbn, accums, Up, Un, Mp, Mn, base);
    row_kernel<<<R, 256, 0, stream>>>(Up, Un, Mp, Mn, bbp, bbn, x, ypos, yneg,
                                      accums, parts, out + 7, base);
  }
  reduce_parts<<<1, 256, 0, stream>>>(parts, accums);
  final_kernel<<<NPTS, 256, 0, stream>>>(accums, out);
}